// Round 1
// baseline (716.942 us; speedup 1.0000x reference)
//
#include <hip/hip_runtime.h>
#include <cstdint>

typedef __bf16 bf16x8 __attribute__((ext_vector_type(8)));
typedef float f32x4 __attribute__((ext_vector_type(4)));
typedef unsigned short u16;

__device__ __forceinline__ u16 f2bf(float f) {
  unsigned u = __builtin_bit_cast(unsigned, f);
  u += 0x7fffu + ((u >> 16) & 1u);   // RNE, matches numpy/jax bf16 cast for finite values
  return (u16)(u >> 16);
}

// ---------------- cast f32 -> bf16 (vectorized, zero-pads tail region) -------
__global__ void cast_f32_bf16(const float* __restrict__ in, u16* __restrict__ out,
                              int n4in, int n4out) {
  int i = blockIdx.x * blockDim.x + threadIdx.x;
  int stride = gridDim.x * blockDim.x;
  for (; i < n4out; i += stride) {
    ushort4 o;
    if (i < n4in) {
      float4 v = ((const float4*)in)[i];
      o.x = f2bf(v.x); o.y = f2bf(v.y); o.z = f2bf(v.z); o.w = f2bf(v.w);
    } else {
      o.x = 0; o.y = 0; o.z = 0; o.w = 0;
    }
    ((ushort4*)out)[i] = o;
  }
}

// ------------- transpose+cast: in [R][C] f32 -> out [C][R] bf16 --------------
__global__ void transpose_cast(const float* __restrict__ in, u16* __restrict__ out,
                               int R, int C) {
  __shared__ float t[64][65];
  int tc = blockIdx.x * 64, tr = blockIdx.y * 64;
  int c = threadIdx.x & 63, r0 = threadIdx.x >> 6;
  #pragma unroll
  for (int p = 0; p < 16; ++p) {
    int r = p * 4 + r0;
    t[r][c] = in[(long)(tr + r) * C + (tc + c)];
  }
  __syncthreads();
  #pragma unroll
  for (int p = 0; p < 16; ++p) {
    int r = p * 4 + r0;
    out[(long)(tc + r) * R + (tr + c)] = f2bf(t[c][r]);
  }
}

// ---------------- 128x128x(K=1024) bf16 GEMM, B^T input, m97-style -----------
// MODE 0: K-half of kv.  A=x_bf (65536x1024), BT=WT_attn rows 0..1023.
//         out: K[b][h][s][d] bf16, bias = b_attn[col].
// MODE 1: V-half transposed. A=WT_v (1024x1024), BT=x_b (4096x1024), per-b (blockIdx.y).
//         out: Vt[b][h][d][s] bf16, bias = b_attn[1024+row] (row bias!).
// MODE 2: q GEMM. A=y_bf (896x1024 padded), BT=WT_mlp. out q[b][h][qi][d] bf16, m<784.
// MODE 3: out GEMM. A=a_bf (896x1024 padded), BT=WT_proj. out f32 [m][n], m<784.
template<int MODE>
__global__ __launch_bounds__(256, 2) void gemm_bt(
    const u16* __restrict__ A, const u16* __restrict__ BT,
    const float* __restrict__ bias, void* __restrict__ outp)
{
  __shared__ u16 As[128][64];
  __shared__ u16 Bs[128][64];

  int bid = blockIdx.x;
  int mt, nt;
  long out_b_off = 0;
  const u16* Ap = A;
  const u16* BTp = BT;
  if constexpr (MODE == 0) {
    int swz = (bid & 7) * 512 + (bid >> 3);      // XCD-contiguous chunks (4096 % 8 == 0)
    mt = swz >> 3; nt = swz & 7;
  } else if constexpr (MODE == 1) {
    int swz = (bid & 7) * 32 + (bid >> 3);       // 256 blocks per b
    nt = swz >> 3; mt = swz & 7;
    int b = blockIdx.y;
    BTp = BT + (long)b * 4096 * 1024;
    out_b_off = (long)b * 1024 * 4096;
  } else {
    mt = bid >> 3; nt = bid & 7;
  }

  int tid = threadIdx.x;
  int l = tid & 63, w = tid >> 6;
  int wr = w >> 1, wc = w & 1;
  int lr = l & 15, lh = l >> 4;

  f32x4 acc[4][4];
  #pragma unroll
  for (int i = 0; i < 4; ++i)
    #pragma unroll
    for (int j = 0; j < 4; ++j)
      acc[i][j] = f32x4{0.f, 0.f, 0.f, 0.f};

  long arow0 = (long)mt * 128;
  long brow0 = (long)nt * 128;
  int srow = w * 8 + (l >> 3);        // staging row within a 32-row pass
  int scol = (l & 7) * 8;             // element offset (16B per lane)
  const u16* ag = Ap + (arow0 + srow) * 1024 + scol;
  const u16* bg = BTp + (brow0 + srow) * 1024 + scol;
  u16* asl = &As[srow][scol];
  u16* bsl = &Bs[srow][scol];

  for (int kt = 0; kt < 16; ++kt) {
    int ko = kt * 64;
    #pragma unroll
    for (int p = 0; p < 4; ++p)
      __builtin_amdgcn_global_load_lds(
          (const __attribute__((address_space(1))) void*)(ag + (long)p * 32 * 1024 + ko),
          (__attribute__((address_space(3))) void*)(asl + p * 32 * 64), 16, 0, 0);
    #pragma unroll
    for (int p = 0; p < 4; ++p)
      __builtin_amdgcn_global_load_lds(
          (const __attribute__((address_space(1))) void*)(bg + (long)p * 32 * 1024 + ko),
          (__attribute__((address_space(3))) void*)(bsl + p * 32 * 64), 16, 0, 0);
    __syncthreads();   // compiler drains vmcnt(0) before s_barrier
    #pragma unroll
    for (int kk = 0; kk < 2; ++kk) {
      bf16x8 af[4], bfr[4];
      #pragma unroll
      for (int m = 0; m < 4; ++m)
        af[m] = *(const bf16x8*)&As[wr * 64 + m * 16 + lr][kk * 32 + lh * 8];
      #pragma unroll
      for (int n = 0; n < 4; ++n)
        bfr[n] = *(const bf16x8*)&Bs[wc * 64 + n * 16 + lr][kk * 32 + lh * 8];
      #pragma unroll
      for (int m = 0; m < 4; ++m)
        #pragma unroll
        for (int n = 0; n < 4; ++n)
          acc[m][n] = __builtin_amdgcn_mfma_f32_16x16x32_bf16(af[m], bfr[n], acc[m][n], 0, 0, 0);
    }
    __syncthreads();
  }

  // epilogue
  #pragma unroll
  for (int m = 0; m < 4; ++m) {
    #pragma unroll
    for (int n = 0; n < 4; ++n) {
      #pragma unroll
      for (int r = 0; r < 4; ++r) {
        int row = (int)arow0 + wr * 64 + m * 16 + lh * 4 + r;
        int col = (int)brow0 + wc * 64 + n * 16 + lr;
        float v = acc[m][n][r];
        if constexpr (MODE == 0) {
          v += bias[col];
          long addr = (long)(row >> 12) * 4194304 + (long)(col >> 6) * 262144
                    + (long)(row & 4095) * 64 + (col & 63);
          ((u16*)outp)[addr] = f2bf(v);
        } else if constexpr (MODE == 1) {
          v += bias[1024 + row];
          ((u16*)outp)[out_b_off + (long)row * 4096 + col] = f2bf(v);
        } else if constexpr (MODE == 2) {
          if (row < 784) {
            v += bias[col];
            int b = row / 49, qi = row - b * 49;
            long addr = ((long)(b * 16 + (col >> 6)) * 64 + qi) * 64 + (col & 63);
            ((u16*)outp)[addr] = f2bf(v);
          }
        } else {
          if (row < 784) {
            v += bias[col];
            ((float*)outp)[(long)row * 1024 + col] = v;
          }
        }
      }
    }
  }
}

// ---------------- fused attention: one workgroup per (b,h) -------------------
// 8 waves: wave = (sh, qm); qm owns q-rows [qm*16, qm*16+16), sh owns s-half.
// Unnormalized accumulation: A += e*v, rsum += e (ones-MFMA); divide at end.
__global__ __launch_bounds__(512, 2) void attn_kernel(
    const u16* __restrict__ Kt, const u16* __restrict__ Vt, const u16* __restrict__ Q,
    const float* __restrict__ mask, u16* __restrict__ Abf)
{
  __shared__ u16 Plds[8192];          // 8 waves x 16x64 bf16 (2KB each)
  __shared__ float red[4][4][4][64];  // cross-wave (sh) reduction for acc_a
  __shared__ float redrs[4][4][64];   // cross-wave reduction for rowsums

  int bh = blockIdx.x;
  int tid = threadIdx.x;
  int l = tid & 63, w = tid >> 6;
  int qm = w & 3, sh = w >> 2;
  int lr = l & 15, lh = l >> 4;

  const u16* Kb = Kt + (long)bh * 262144;   // [s][d] rows of 64
  const u16* Vb = Vt + (long)bh * 262144;   // [d][s] rows of 4096
  const u16* Qb = Q  + (long)bh * 4096;     // [qi][d]

  bf16x8 qf[2];
  #pragma unroll
  for (int kf = 0; kf < 2; ++kf)
    qf[kf] = *(const bf16x8*)(Qb + (qm * 16 + lr) * 64 + kf * 32 + lh * 8);

  bf16x8 ones;
  #pragma unroll
  for (int j = 0; j < 8; ++j) ones[j] = (__bf16)1.0f;

  f32x4 acc_a[4];
  #pragma unroll
  for (int n = 0; n < 4; ++n) acc_a[n] = f32x4{0.f, 0.f, 0.f, 0.f};
  f32x4 acc_rs = f32x4{0.f, 0.f, 0.f, 0.f};

  char* Pw = (char*)Plds + w * 2048;

  for (int it = 0; it < 32; ++it) {
    int s0 = (it * 2 + sh) * 64;
    // QK^T: logits[q][s] for 16 q x 64 s
    f32x4 lg[4];
    #pragma unroll
    for (int sf = 0; sf < 4; ++sf) {
      const u16* kp = Kb + (long)(s0 + sf * 16 + lr) * 64 + lh * 8;
      bf16x8 k0 = *(const bf16x8*)(kp);
      bf16x8 k1 = *(const bf16x8*)(kp + 32);
      f32x4 t = f32x4{0.f, 0.f, 0.f, 0.f};
      t = __builtin_amdgcn_mfma_f32_16x16x32_bf16(qf[0], k0, t, 0, 0, 0);
      t = __builtin_amdgcn_mfma_f32_16x16x32_bf16(qf[1], k1, t, 0, 0, 0);
      lg[sf] = t;
    }
    // e = exp(w/8)*mask -> P in LDS (per-wave region, XOR-swizzled)
    #pragma unroll
    for (int sf = 0; sf < 4; ++sf) {
      #pragma unroll
      for (int r = 0; r < 4; ++r) {
        int qq = lh * 4 + r;
        int q = qm * 16 + qq;
        int s = s0 + sf * 16 + lr;
        float mv = (q < 49) ? mask[(long)q * 4096 + s] : 0.f;
        float e = __expf(lg[sf][r] * 0.125f) * mv;
        int byte = (qq * 128 + (sf * 16 + lr) * 2) ^ ((qq & 7) << 4);
        *(u16*)(Pw + byte) = f2bf(e);
      }
    }
    // PV + rowsum (P read back as A-fragments)
    #pragma unroll
    for (int k2 = 0; k2 < 2; ++k2) {
      int byte = (lr * 128 + k2 * 64 + lh * 16) ^ ((lr & 7) << 4);
      bf16x8 pf;
      __builtin_memcpy(&pf, Pw + byte, 16);
      #pragma unroll
      for (int n = 0; n < 4; ++n) {
        bf16x8 vf = *(const bf16x8*)(Vb + (long)(n * 16 + lr) * 4096 + s0 + k2 * 32 + lh * 8);
        acc_a[n] = __builtin_amdgcn_mfma_f32_16x16x32_bf16(pf, vf, acc_a[n], 0, 0, 0);
      }
      acc_rs = __builtin_amdgcn_mfma_f32_16x16x32_bf16(pf, ones, acc_rs, 0, 0, 0);
    }
  }

  // reduce the two s-halves, normalize, write
  if (sh == 1) {
    #pragma unroll
    for (int n = 0; n < 4; ++n)
      #pragma unroll
      for (int r = 0; r < 4; ++r)
        red[qm][n][r][l] = acc_a[n][r];
    #pragma unroll
    for (int r = 0; r < 4; ++r) redrs[qm][r][l] = acc_rs[r];
  }
  __syncthreads();
  if (sh == 0) {
    int b = bh >> 4, h = bh & 15;
    #pragma unroll
    for (int r = 0; r < 4; ++r) {
      int q = qm * 16 + lh * 4 + r;
      if (q < 49) {
        float rs = acc_rs[r] + redrs[qm][r][l] + 1e-6f;
        #pragma unroll
        for (int n = 0; n < 4; ++n) {
          float v = (acc_a[n][r] + red[qm][n][r][l]) / rs;
          Abf[(long)(b * 49 + q) * 1024 + h * 64 + n * 16 + lr] = f2bf(v);
        }
      }
    }
  }
}

// -----------------------------------------------------------------------------
extern "C" void kernel_launch(void* const* d_in, const int* in_sizes, int n_in,
                              void* d_out, int out_size, void* d_ws, size_t ws_size,
                              hipStream_t stream) {
  const float* x      = (const float*)d_in[0];
  const float* y      = (const float*)d_in[1];
  const float* mask   = (const float*)d_in[2];
  const float* b_attn = (const float*)d_in[4];
  const float* W_attn = (const float*)d_in[3];
  const float* W_mlp  = (const float*)d_in[5];
  const float* b_mlp  = (const float*)d_in[6];
  const float* W_proj = (const float*)d_in[7];
  const float* b_proj = (const float*)d_in[8];

  if (ws_size < 416808960ULL) return;  // need ~397.5 MB of scratch

  char* ws = (char*)d_ws;
  u16* x_bf    = (u16*)(ws);                   // 128 MB  [65536][1024]
  u16* Kt      = (u16*)(ws + 134217728L);      // 128 MB  [b][h][s][d]
  u16* Vt      = (u16*)(ws + 268435456L);      // 128 MB  [b][h][d][s]
  u16* WT_attn = (u16*)(ws + 402653184L);      // 4 MB    [2048][1024]
  u16* WT_mlp  = (u16*)(ws + 406847488L);      // 2 MB
  u16* WT_proj = (u16*)(ws + 408944640L);      // 2 MB
  u16* y_bf    = (u16*)(ws + 411041792L);      // 1.75 MB [896][1024] (zero-padded)
  u16* q_ws    = (u16*)(ws + 412876800L);      // 2 MB    [b][h][64][64]
  u16* a_bf    = (u16*)(ws + 414973952L);      // 1.75 MB [896][1024]

  cast_f32_bf16<<<2048, 256, 0, stream>>>(x, x_bf, 16777216, 16777216);
  cast_f32_bf16<<<896, 256, 0, stream>>>(y, y_bf, 200704, 229376);
  transpose_cast<<<dim3(32, 16), 256, 0, stream>>>(W_attn, WT_attn, 1024, 2048);
  transpose_cast<<<dim3(16, 16), 256, 0, stream>>>(W_mlp, WT_mlp, 1024, 1024);
  transpose_cast<<<dim3(16, 16), 256, 0, stream>>>(W_proj, WT_proj, 1024, 1024);

  gemm_bt<0><<<4096, 256, 0, stream>>>(x_bf, WT_attn, b_attn, Kt);
  gemm_bt<1><<<dim3(256, 16), 256, 0, stream>>>(WT_attn + 1048576, x_bf, b_attn, Vt);
  gemm_bt<2><<<56, 256, 0, stream>>>(y_bf, WT_mlp, b_mlp, q_ws);

  attn_kernel<<<256, 512, 0, stream>>>(Kt, Vt, q_ws, mask, a_bf);

  gemm_bt<3><<<56, 256, 0, stream>>>(a_bf, WT_proj, b_proj, d_out);
}

// Round 2
// 634.717 us; speedup vs baseline: 1.1295x; 1.1295x over previous
//
#include <hip/hip_runtime.h>
#include <cstdint>

typedef __bf16 bf16x8 __attribute__((ext_vector_type(8)));
typedef float f32x4 __attribute__((ext_vector_type(4)));
typedef unsigned short u16;

__device__ __forceinline__ u16 f2bf(float f) {
  unsigned u = __builtin_bit_cast(unsigned, f);
  u += 0x7fffu + ((u >> 16) & 1u);   // RNE, matches numpy/jax bf16 cast for finite values
  return (u16)(u >> 16);
}

// ---------------- cast f32 -> bf16 (vectorized, zero-pads tail region) -------
__global__ void cast_f32_bf16(const float* __restrict__ in, u16* __restrict__ out,
                              int n4in, int n4out) {
  int i = blockIdx.x * blockDim.x + threadIdx.x;
  int stride = gridDim.x * blockDim.x;
  for (; i < n4out; i += stride) {
    ushort4 o;
    if (i < n4in) {
      float4 v = ((const float4*)in)[i];
      o.x = f2bf(v.x); o.y = f2bf(v.y); o.z = f2bf(v.z); o.w = f2bf(v.w);
    } else {
      o.x = 0; o.y = 0; o.z = 0; o.w = 0;
    }
    ((ushort4*)out)[i] = o;
  }
}

// ------------- transpose+cast: in [R][C] f32 -> out [C][R] bf16 --------------
__global__ void transpose_cast(const float* __restrict__ in, u16* __restrict__ out,
                               int R, int C) {
  __shared__ float t[64][65];
  int tc = blockIdx.x * 64, tr = blockIdx.y * 64;
  int c = threadIdx.x & 63, r0 = threadIdx.x >> 6;
  #pragma unroll
  for (int p = 0; p < 16; ++p) {
    int r = p * 4 + r0;
    t[r][c] = in[(long)(tr + r) * C + (tc + c)];
  }
  __syncthreads();
  #pragma unroll
  for (int p = 0; p < 16; ++p) {
    int r = p * 4 + r0;
    out[(long)(tc + r) * R + (tr + c)] = f2bf(t[c][r]);
  }
}

// ---------------- 128x128x(K=1024) bf16 GEMM, B^T input, m97-style -----------
template<int MODE>
__global__ __launch_bounds__(256, 2) void gemm_bt(
    const u16* __restrict__ A, const u16* __restrict__ BT,
    const float* __restrict__ bias, void* __restrict__ outp)
{
  __shared__ u16 As[128][64];
  __shared__ u16 Bs[128][64];

  int bid = blockIdx.x;
  int mt, nt;
  long out_b_off = 0;
  const u16* Ap = A;
  const u16* BTp = BT;
  if constexpr (MODE == 0) {
    int swz = (bid & 7) * 512 + (bid >> 3);      // XCD-contiguous chunks (4096 % 8 == 0)
    mt = swz >> 3; nt = swz & 7;
  } else if constexpr (MODE == 1) {
    int swz = (bid & 7) * 32 + (bid >> 3);       // 256 blocks per b
    nt = swz >> 3; mt = swz & 7;
    int b = blockIdx.y;
    BTp = BT + (long)b * 4096 * 1024;
    out_b_off = (long)b * 1024 * 4096;
  } else {
    mt = bid >> 3; nt = bid & 7;
  }

  int tid = threadIdx.x;
  int l = tid & 63, w = tid >> 6;
  int wr = w >> 1, wc = w & 1;
  int lr = l & 15, lh = l >> 4;

  f32x4 acc[4][4];
  #pragma unroll
  for (int i = 0; i < 4; ++i)
    #pragma unroll
    for (int j = 0; j < 4; ++j)
      acc[i][j] = f32x4{0.f, 0.f, 0.f, 0.f};

  long arow0 = (long)mt * 128;
  long brow0 = (long)nt * 128;
  int srow = w * 8 + (l >> 3);        // staging row within a 32-row pass
  int scol = (l & 7) * 8;             // element offset (16B per lane)
  const u16* ag = Ap + (arow0 + srow) * 1024 + scol;
  const u16* bg = BTp + (brow0 + srow) * 1024 + scol;
  u16* asl = &As[srow][scol];
  u16* bsl = &Bs[srow][scol];

  for (int kt = 0; kt < 16; ++kt) {
    int ko = kt * 64;
    #pragma unroll
    for (int p = 0; p < 4; ++p)
      __builtin_amdgcn_global_load_lds(
          (const __attribute__((address_space(1))) void*)(ag + (long)p * 32 * 1024 + ko),
          (__attribute__((address_space(3))) void*)(asl + p * 32 * 64), 16, 0, 0);
    #pragma unroll
    for (int p = 0; p < 4; ++p)
      __builtin_amdgcn_global_load_lds(
          (const __attribute__((address_space(1))) void*)(bg + (long)p * 32 * 1024 + ko),
          (__attribute__((address_space(3))) void*)(bsl + p * 32 * 64), 16, 0, 0);
    __syncthreads();   // compiler drains vmcnt(0) before s_barrier
    #pragma unroll
    for (int kk = 0; kk < 2; ++kk) {
      bf16x8 af[4], bfr[4];
      #pragma unroll
      for (int m = 0; m < 4; ++m)
        af[m] = *(const bf16x8*)&As[wr * 64 + m * 16 + lr][kk * 32 + lh * 8];
      #pragma unroll
      for (int n = 0; n < 4; ++n)
        bfr[n] = *(const bf16x8*)&Bs[wc * 64 + n * 16 + lr][kk * 32 + lh * 8];
      #pragma unroll
      for (int m = 0; m < 4; ++m)
        #pragma unroll
        for (int n = 0; n < 4; ++n)
          acc[m][n] = __builtin_amdgcn_mfma_f32_16x16x32_bf16(af[m], bfr[n], acc[m][n], 0, 0, 0);
    }
    __syncthreads();
  }

  // epilogue
  #pragma unroll
  for (int m = 0; m < 4; ++m) {
    #pragma unroll
    for (int n = 0; n < 4; ++n) {
      #pragma unroll
      for (int r = 0; r < 4; ++r) {
        int row = (int)arow0 + wr * 64 + m * 16 + lh * 4 + r;
        int col = (int)brow0 + wc * 64 + n * 16 + lr;
        float v = acc[m][n][r];
        if constexpr (MODE == 0) {
          v += bias[col];
          long addr = (long)(row >> 12) * 4194304 + (long)(col >> 6) * 262144
                    + (long)(row & 4095) * 64 + (col & 63);
          ((u16*)outp)[addr] = f2bf(v);
        } else if constexpr (MODE == 1) {
          v += bias[1024 + row];
          ((u16*)outp)[out_b_off + (long)row * 4096 + col] = f2bf(v);
        } else if constexpr (MODE == 2) {
          if (row < 784) {
            v += bias[col];
            int b = row / 49, qi = row - b * 49;
            long addr = ((long)(b * 16 + (col >> 6)) * 64 + qi) * 64 + (col & 63);
            ((u16*)outp)[addr] = f2bf(v);
          }
        } else {
          if (row < 784) {
            v += bias[col];
            ((float*)outp)[(long)row * 1024 + col] = v;
          }
        }
      }
    }
  }
}

// ---------------- fused attention partials: one wg per (b,h,s-chunk) ---------
// 8 waves: wave = (sh, qm); qm owns q-rows [qm*16, qm*16+16), sh owns s-half of
// each 128-s stripe. chunk = blockIdx.y owns s in [chunk*1024, chunk*1024+1024).
// Unnormalized: partA += e*v, prs += e (ones-MFMA); normalize in attn_reduce.
__global__ __launch_bounds__(512, 2) void attn_part(
    const u16* __restrict__ Kt, const u16* __restrict__ Vt, const u16* __restrict__ Q,
    const float* __restrict__ mask,
    float* __restrict__ partA, float* __restrict__ prs)
{
  __shared__ u16 Plds[8192];          // 8 waves x 16x64 bf16 (2KB each)
  __shared__ float red[4][4][4][64];  // cross-wave (sh) reduction for acc_a
  __shared__ float redrs[4][4][64];   // cross-wave reduction for rowsums

  int bh = blockIdx.x;
  int chunk = blockIdx.y;
  int tid = threadIdx.x;
  int l = tid & 63, w = tid >> 6;
  int qm = w & 3, sh = w >> 2;
  int lr = l & 15, lh = l >> 4;

  const u16* Kb = Kt + (long)bh * 262144;   // [s][d] rows of 64
  const u16* Vb = Vt + (long)bh * 262144;   // [d][s] rows of 4096
  const u16* Qb = Q  + (long)bh * 4096;     // [qi][d]

  bf16x8 qf[2];
  #pragma unroll
  for (int kf = 0; kf < 2; ++kf)
    qf[kf] = *(const bf16x8*)(Qb + (qm * 16 + lr) * 64 + kf * 32 + lh * 8);

  bf16x8 ones;
  #pragma unroll
  for (int j = 0; j < 8; ++j) ones[j] = (__bf16)1.0f;

  f32x4 acc_a[4];
  #pragma unroll
  for (int n = 0; n < 4; ++n) acc_a[n] = f32x4{0.f, 0.f, 0.f, 0.f};
  f32x4 acc_rs = f32x4{0.f, 0.f, 0.f, 0.f};

  char* Pw = (char*)Plds + w * 2048;

  for (int it = 0; it < 8; ++it) {
    int s0 = chunk * 1024 + (it * 2 + sh) * 64;
    // QK^T: logits[q][s] for 16 q x 64 s
    f32x4 lg[4];
    #pragma unroll
    for (int sf = 0; sf < 4; ++sf) {
      const u16* kp = Kb + (long)(s0 + sf * 16 + lr) * 64 + lh * 8;
      bf16x8 k0 = *(const bf16x8*)(kp);
      bf16x8 k1 = *(const bf16x8*)(kp + 32);
      f32x4 t = f32x4{0.f, 0.f, 0.f, 0.f};
      t = __builtin_amdgcn_mfma_f32_16x16x32_bf16(qf[0], k0, t, 0, 0, 0);
      t = __builtin_amdgcn_mfma_f32_16x16x32_bf16(qf[1], k1, t, 0, 0, 0);
      lg[sf] = t;
    }
    // e = exp(w/8)*mask -> P in LDS (per-wave region, XOR-swizzled)
    #pragma unroll
    for (int sf = 0; sf < 4; ++sf) {
      #pragma unroll
      for (int r = 0; r < 4; ++r) {
        int qq = lh * 4 + r;
        int q = qm * 16 + qq;
        int s = s0 + sf * 16 + lr;
        float mv = (q < 49) ? mask[(long)q * 4096 + s] : 0.f;
        float e = __expf(lg[sf][r] * 0.125f) * mv;
        int byte = (qq * 128 + (sf * 16 + lr) * 2) ^ ((qq & 7) << 4);
        *(u16*)(Pw + byte) = f2bf(e);
      }
    }
    // PV + rowsum (P read back as A-fragments)
    #pragma unroll
    for (int k2 = 0; k2 < 2; ++k2) {
      int byte = (lr * 128 + k2 * 64 + lh * 16) ^ ((lr & 7) << 4);
      bf16x8 pf;
      __builtin_memcpy(&pf, Pw + byte, 16);
      #pragma unroll
      for (int n = 0; n < 4; ++n) {
        bf16x8 vf = *(const bf16x8*)(Vb + (long)(n * 16 + lr) * 4096 + s0 + k2 * 32 + lh * 8);
        acc_a[n] = __builtin_amdgcn_mfma_f32_16x16x32_bf16(pf, vf, acc_a[n], 0, 0, 0);
      }
      acc_rs = __builtin_amdgcn_mfma_f32_16x16x32_bf16(pf, ones, acc_rs, 0, 0, 0);
    }
  }

  // reduce the two s-halves, write unnormalized partials
  if (sh == 1) {
    #pragma unroll
    for (int n = 0; n < 4; ++n)
      #pragma unroll
      for (int r = 0; r < 4; ++r)
        red[qm][n][r][l] = acc_a[n][r];
    #pragma unroll
    for (int r = 0; r < 4; ++r) redrs[qm][r][l] = acc_rs[r];
  }
  __syncthreads();
  if (sh == 0) {
    long base = ((long)bh * 4 + chunk) * 64;
    #pragma unroll
    for (int r = 0; r < 4; ++r) {
      int q = qm * 16 + lh * 4 + r;
      float rs = acc_rs[r] + redrs[qm][r][l];
      if (lr == 0) prs[base + q] = rs;
      #pragma unroll
      for (int n = 0; n < 4; ++n)
        partA[(base + q) * 64 + n * 16 + lr] = acc_a[n][r] + red[qm][n][r][l];
    }
  }
}

// ---------------- reduce 4 s-chunk partials, normalize, write a_bf -----------
__global__ __launch_bounds__(256) void attn_reduce(
    const float* __restrict__ partA, const float* __restrict__ prs,
    u16* __restrict__ Abf)
{
  int bh = blockIdx.x;
  int t = threadIdx.x;
  int q = t >> 2, d0 = (t & 3) * 16;
  if (q >= 49) return;
  int b = bh >> 4, h = bh & 15;

  float rs = 1e-6f;
  #pragma unroll
  for (int c = 0; c < 4; ++c) rs += prs[((long)bh * 4 + c) * 64 + q];

  #pragma unroll
  for (int j = 0; j < 4; ++j) {
    float4 s = float4{0.f, 0.f, 0.f, 0.f};
    #pragma unroll
    for (int c = 0; c < 4; ++c) {
      float4 v = *(const float4*)(partA + (((long)bh * 4 + c) * 64 + q) * 64 + d0 + j * 4);
      s.x += v.x; s.y += v.y; s.z += v.z; s.w += v.w;
    }
    ushort4 o;
    o.x = f2bf(s.x / rs); o.y = f2bf(s.y / rs);
    o.z = f2bf(s.z / rs); o.w = f2bf(s.w / rs);
    *(ushort4*)(Abf + ((long)(b * 49 + q) * 1024 + h * 64 + d0 + j * 4)) = o;
  }
}

// -----------------------------------------------------------------------------
extern "C" void kernel_launch(void* const* d_in, const int* in_sizes, int n_in,
                              void* d_out, int out_size, void* d_ws, size_t ws_size,
                              hipStream_t stream) {
  const float* x      = (const float*)d_in[0];
  const float* y      = (const float*)d_in[1];
  const float* mask   = (const float*)d_in[2];
  const float* W_attn = (const float*)d_in[3];
  const float* b_attn = (const float*)d_in[4];
  const float* W_mlp  = (const float*)d_in[5];
  const float* b_mlp  = (const float*)d_in[6];
  const float* W_proj = (const float*)d_in[7];
  const float* b_proj = (const float*)d_in[8];

  if (ws_size < 416808960ULL) return;  // need ~397.5 MB of scratch

  char* ws = (char*)d_ws;
  u16* x_bf    = (u16*)(ws);                   // 128 MB  [65536][1024]
  u16* Kt      = (u16*)(ws + 134217728L);      // 128 MB  [b][h][s][d]
  u16* Vt      = (u16*)(ws + 268435456L);      // 128 MB  [b][h][d][s]
  u16* WT_attn = (u16*)(ws + 402653184L);      // 4 MB    [2048][1024]
  u16* WT_mlp  = (u16*)(ws + 406847488L);      // 2 MB
  u16* WT_proj = (u16*)(ws + 408944640L);      // 2 MB
  u16* y_bf    = (u16*)(ws + 411041792L);      // 1.75 MB [896][1024] (zero-padded)
  u16* q_ws    = (u16*)(ws + 412876800L);      // 2 MB    [b][h][64][64]
  u16* a_bf    = (u16*)(ws + 414973952L);      // 1.75 MB [896][1024]
  // attention partials REUSE the x_bf region (x_bf is dead after gemm_bt<1>;
  // cast_f32_bf16 fully rewrites it at the start of every call)
  float* partA = (float*)(ws);                 // 16 MB   [bh][chunk][64q][64d]
  float* prs   = (float*)(ws + 16777216L);     // 256 KB  [bh][chunk][64q]

  cast_f32_bf16<<<2048, 256, 0, stream>>>(x, x_bf, 16777216, 16777216);
  cast_f32_bf16<<<896, 256, 0, stream>>>(y, y_bf, 200704, 229376);
  transpose_cast<<<dim3(32, 16), 256, 0, stream>>>(W_attn, WT_attn, 1024, 2048);
  transpose_cast<<<dim3(16, 16), 256, 0, stream>>>(W_mlp, WT_mlp, 1024, 1024);
  transpose_cast<<<dim3(16, 16), 256, 0, stream>>>(W_proj, WT_proj, 1024, 1024);

  gemm_bt<0><<<4096, 256, 0, stream>>>(x_bf, WT_attn, b_attn, Kt);
  gemm_bt<1><<<dim3(256, 16), 256, 0, stream>>>(WT_attn + 1048576, x_bf, b_attn, Vt);
  gemm_bt<2><<<56, 256, 0, stream>>>(y_bf, WT_mlp, b_mlp, q_ws);

  attn_part<<<dim3(256, 4), 512, 0, stream>>>(Kt, Vt, q_ws, mask, partA, prs);
  attn_reduce<<<256, 256, 0, stream>>>(partA, prs, a_bf);

  gemm_bt<3><<<56, 256, 0, stream>>>(a_bf, WT_proj, b_proj, d_out);
}

// Round 3
// 589.076 us; speedup vs baseline: 1.2171x; 1.0775x over previous
//
#include <hip/hip_runtime.h>
#include <cstdint>

typedef __bf16 bf16x8 __attribute__((ext_vector_type(8)));
typedef float f32x4 __attribute__((ext_vector_type(4)));
typedef unsigned short u16;

#define GBAR() asm volatile("s_barrier" ::: "memory")
#define LGKM0() do { asm volatile("s_waitcnt lgkmcnt(0)" ::: "memory"); \
                     __builtin_amdgcn_sched_barrier(0); } while (0)
#define VM10() asm volatile("s_waitcnt vmcnt(10)" ::: "memory")
#define MFMA16(a, b, c) __builtin_amdgcn_mfma_f32_16x16x32_bf16((a), (b), (c), 0, 0, 0)

__device__ __forceinline__ u16 f2bf(float f) {
  unsigned u = __builtin_bit_cast(unsigned, f);
  u += 0x7fffu + ((u >> 16) & 1u);   // RNE, matches numpy/jax bf16 cast
  return (u16)(u >> 16);
}

// ---------------- cast f32 -> bf16 (vectorized, zero-pads tail region) -------
__global__ void cast_f32_bf16(const float* __restrict__ in, u16* __restrict__ out,
                              int n4in, int n4out) {
  int i = blockIdx.x * blockDim.x + threadIdx.x;
  int stride = gridDim.x * blockDim.x;
  for (; i < n4out; i += stride) {
    ushort4 o;
    if (i < n4in) {
      float4 v = ((const float4*)in)[i];
      o.x = f2bf(v.x); o.y = f2bf(v.y); o.z = f2bf(v.z); o.w = f2bf(v.w);
    } else {
      o.x = 0; o.y = 0; o.z = 0; o.w = 0;
    }
    ((ushort4*)out)[i] = o;
  }
}

// ------------- transpose+cast: in [R][C] f32 -> out [C][R] bf16 --------------
__global__ void transpose_cast(const float* __restrict__ in, u16* __restrict__ out,
                               int R, int C) {
  __shared__ float t[64][65];
  int tc = blockIdx.x * 64, tr = blockIdx.y * 64;
  int c = threadIdx.x & 63, r0 = threadIdx.x >> 6;
  #pragma unroll
  for (int p = 0; p < 16; ++p) {
    int r = p * 4 + r0;
    t[r][c] = in[(long)(tr + r) * C + (tc + c)];
  }
  __syncthreads();
  #pragma unroll
  for (int p = 0; p < 16; ++p) {
    int r = p * 4 + r0;
    out[(long)(tc + r) * R + (tr + c)] = f2bf(t[c][r]);
  }
}

// =============== 256x256x(K=1024) bf16 GEMM, 8-phase-style schedule ==========
// 8 waves (2M x 4N), BK=64, double-buffered LDS (128 KiB), counted vmcnt(10),
// st-swizzled LDS (pre-swizzled global source + XOR on ds_read), setprio MFMA.
// MODE 0: K-half of kv. A=x_bf (65536x1024), BT=WT_attn rows 0..1023.
//         out K[b][h][s][d] bf16, bias=b_attn[col].
// MODE 1: V-half transposed, per-batch (blockIdx.y). A=WT_v (1024x1024),
//         BT=x_b (4096x1024). out Vt[b][h][d][s] bf16, bias=b_attn[1024+row].
template<int MODE>
__global__ __launch_bounds__(512, 2) void gemm256(
    const u16* __restrict__ A, const u16* __restrict__ BT,
    const float* __restrict__ bias, void* __restrict__ outp)
{
  __shared__ __align__(16) char lds[131072];  // [2 buf][A 32K | B 32K]

  int tid = threadIdx.x;
  int l = tid & 63, w = tid >> 6;
  int wr = w >> 2, wc = w & 3;
  int lr = l & 15, lh = l >> 4;

  int bid = blockIdx.x;
  int mt, nt;
  long out_off = 0;
  const u16* Ap = A;
  const u16* BTp = BT;
  if constexpr (MODE == 0) {
    int wg = (bid & 7) * 128 + (bid >> 3);   // XCD-contiguous (1024 % 8 == 0)
    mt = wg >> 2; nt = wg & 3;
  } else {
    int wg = (bid & 7) * 8 + (bid >> 3);     // 64 blocks per batch
    mt = wg & 3; nt = wg >> 2;
    int b = blockIdx.y;
    BTp = BT + (long)b * 4194304;
    out_off = (long)b * 4194304;
  }
  long Arow0 = (long)mt * 256;
  long Brow0 = (long)nt * 256;

  // ---- staging address setup (pre-swizzled global source, linear LDS dest) --
  int rho = (w << 3) + (l >> 3);                 // 0..63: row within a 64-row slab
  int csw = ((l & 7) ^ (l >> 3)) << 3;           // swizzled col chunk (elements)
  const u16* agA = Ap + (Arow0 + rho) * 1024 + csw;
  int browoff = (w >> 2) * 64 + (w & 3) * 8 + (l >> 3);
  const u16* agB = BTp + (Brow0 + browoff) * 1024 + csw;
  char* ldsAthr = lds + rho * 128 + (l & 7) * 16;
  char* ldsBthr = lds + 32768 + browoff * 128 + (l & 7) * 16;

  // stage A half (mh): rows {mh*64..+64, 128+mh*64..+64}; 2 loads/thread
  auto SA = [&](int dt, int st, int mh) {
    char* d = ldsAthr + (dt & 1) * 65536 + mh * 8192;
    const u16* s = agA + (long)st * 64 + mh * 65536;
    __builtin_amdgcn_global_load_lds(
        (const __attribute__((address_space(1))) void*)s,
        (__attribute__((address_space(3))) void*)d, 16, 0, 0);
    __builtin_amdgcn_global_load_lds(
        (const __attribute__((address_space(1))) void*)(s + 131072),
        (__attribute__((address_space(3))) void*)(d + 16384), 16, 0, 0);
  };
  // stage B half (h): rows {beta*64 + h*32 ..+32} for beta=0..3
  auto SB = [&](int dt, int st, int h) {
    char* d = ldsBthr + (dt & 1) * 65536 + h * 4096;
    const u16* s = agB + (long)st * 64 + h * 32768;
    __builtin_amdgcn_global_load_lds(
        (const __attribute__((address_space(1))) void*)s,
        (__attribute__((address_space(3))) void*)d, 16, 0, 0);
    __builtin_amdgcn_global_load_lds(
        (const __attribute__((address_space(1))) void*)(s + 131072),
        (__attribute__((address_space(3))) void*)(d + 16384), 16, 0, 0);
  };

  // ---- fragment-read offsets (swizzle XOR'd per row) ------------------------
  int arow_b = (wr * 128 + lr) * 128;
  int brow_b = (wc * 64 + lr) * 128 + 32768;
  int xr0 = (lh ^ (lr & 7)) << 4;
  int xr1 = ((4 + lh) ^ (lr & 7)) << 4;

  f32x4 acc[8][4];
  #pragma unroll
  for (int m = 0; m < 8; ++m)
    #pragma unroll
    for (int n = 0; n < 4; ++n) acc[m][n] = f32x4{0.f, 0.f, 0.f, 0.f};

  bf16x8 af[4][2], bn0[2][2], bn1[2][2];

  // ---- prologue: 7 half-tiles in flight (14 loads) ---------------------------
  SA(0, 0, 0); SB(0, 0, 0); SB(0, 0, 1); SA(0, 0, 1);
  SA(1, 1, 0); SB(1, 1, 0); SB(1, 1, 1);
  VM10(); GBAR();

  for (int t = 0; t < 16; ++t) {
    int buf = (t & 1) << 16;
    // ---- P1: read A-half0 + B n=0,1 | stage A1(t+1) | MFMA m0-3 x n0-1 ----
    #pragma unroll
    for (int m = 0; m < 4; ++m) {
      af[m][0] = *(const bf16x8*)(lds + buf + arow_b + m * 2048 + xr0);
      af[m][1] = *(const bf16x8*)(lds + buf + arow_b + m * 2048 + xr1);
    }
    #pragma unroll
    for (int n = 0; n < 2; ++n) {
      bn0[n][0] = *(const bf16x8*)(lds + buf + brow_b + n * 2048 + xr0);
      bn0[n][1] = *(const bf16x8*)(lds + buf + brow_b + n * 2048 + xr1);
    }
    { int tt = t + 1; SA(tt, tt < 16 ? tt : 15, 1); }
    GBAR(); LGKM0();
    __builtin_amdgcn_s_setprio(1);
    #pragma unroll
    for (int m = 0; m < 4; ++m)
      #pragma unroll
      for (int n = 0; n < 2; ++n) {
        acc[m][n] = MFMA16(af[m][0], bn0[n][0], acc[m][n]);
        acc[m][n] = MFMA16(af[m][1], bn0[n][1], acc[m][n]);
      }
    __builtin_amdgcn_s_setprio(0);
    VM10(); GBAR();
    // ---- P2: read B n=2,3 | stage A0(t+2) | MFMA m0-3 x n2-3 --------------
    #pragma unroll
    for (int n = 0; n < 2; ++n) {
      bn1[n][0] = *(const bf16x8*)(lds + buf + brow_b + 4096 + n * 2048 + xr0);
      bn1[n][1] = *(const bf16x8*)(lds + buf + brow_b + 4096 + n * 2048 + xr1);
    }
    { int tt = t + 2; SA(tt, tt < 16 ? tt : 15, 0); }
    GBAR(); LGKM0();
    __builtin_amdgcn_s_setprio(1);
    #pragma unroll
    for (int m = 0; m < 4; ++m)
      #pragma unroll
      for (int n = 0; n < 2; ++n) {
        acc[m][2 + n] = MFMA16(af[m][0], bn1[n][0], acc[m][2 + n]);
        acc[m][2 + n] = MFMA16(af[m][1], bn1[n][1], acc[m][2 + n]);
      }
    __builtin_amdgcn_s_setprio(0);
    VM10(); GBAR();
    // ---- P3: read A-half1 | stage B-h0(t+2) | MFMA m4-7 x n0-1 ------------
    #pragma unroll
    for (int m = 0; m < 4; ++m) {
      af[m][0] = *(const bf16x8*)(lds + buf + arow_b + 8192 + m * 2048 + xr0);
      af[m][1] = *(const bf16x8*)(lds + buf + arow_b + 8192 + m * 2048 + xr1);
    }
    { int tt = t + 2; SB(tt, tt < 16 ? tt : 15, 0); }
    GBAR(); LGKM0();
    __builtin_amdgcn_s_setprio(1);
    #pragma unroll
    for (int m = 0; m < 4; ++m)
      #pragma unroll
      for (int n = 0; n < 2; ++n) {
        acc[4 + m][n] = MFMA16(af[m][0], bn0[n][0], acc[4 + m][n]);
        acc[4 + m][n] = MFMA16(af[m][1], bn0[n][1], acc[4 + m][n]);
      }
    __builtin_amdgcn_s_setprio(0);
    GBAR();
    // ---- P4: stage B-h1(t+2) | MFMA m4-7 x n2-3 ----------------------------
    { int tt = t + 2; SB(tt, tt < 16 ? tt : 15, 1); }
    GBAR();
    __builtin_amdgcn_s_setprio(1);
    #pragma unroll
    for (int m = 0; m < 4; ++m)
      #pragma unroll
      for (int n = 0; n < 2; ++n) {
        acc[4 + m][2 + n] = MFMA16(af[m][0], bn1[n][0], acc[4 + m][2 + n]);
        acc[4 + m][2 + n] = MFMA16(af[m][1], bn1[n][1], acc[4 + m][2 + n]);
      }
    __builtin_amdgcn_s_setprio(0);
    VM10(); GBAR();
  }

  asm volatile("s_waitcnt vmcnt(0)" ::: "memory");  // drain tail junk stages

  // ---- epilogue --------------------------------------------------------------
  #pragma unroll
  for (int m = 0; m < 8; ++m) {
    #pragma unroll
    for (int n = 0; n < 4; ++n) {
      #pragma unroll
      for (int r = 0; r < 4; ++r) {
        long row = Arow0 + wr * 128 + m * 16 + lh * 4 + r;
        long col = Brow0 + wc * 64 + n * 16 + lr;
        float v = acc[m][n][r];
        if constexpr (MODE == 0) {
          v += bias[col];
          long addr = (row >> 12) * 4194304 + (col >> 6) * 262144
                    + (row & 4095) * 64 + (col & 63);
          ((u16*)outp)[addr] = f2bf(v);
        } else {
          v += bias[1024 + row];
          ((u16*)outp)[out_off + row * 4096 + col] = f2bf(v);
        }
      }
    }
  }
}

// ---------------- 128x128x(K=1024) bf16 GEMM for the small matmuls -----------
// MODE 2: q GEMM. A=y_bf (896x1024 padded), BT=WT_mlp. out q[b][h][qi][d] bf16.
// MODE 3: out GEMM. A=a_bf (896x1024 padded), BT=WT_proj. out f32 [m][n], m<784.
template<int MODE>
__global__ __launch_bounds__(256, 2) void gemm_bt(
    const u16* __restrict__ A, const u16* __restrict__ BT,
    const float* __restrict__ bias, void* __restrict__ outp)
{
  __shared__ u16 As[128][64];
  __shared__ u16 Bs[128][64];

  int bid = blockIdx.x;
  int mt = bid >> 3, nt = bid & 7;

  int tid = threadIdx.x;
  int l = tid & 63, w = tid >> 6;
  int wr = w >> 1, wc = w & 1;
  int lr = l & 15, lh = l >> 4;

  f32x4 acc[4][4];
  #pragma unroll
  for (int i = 0; i < 4; ++i)
    #pragma unroll
    for (int j = 0; j < 4; ++j)
      acc[i][j] = f32x4{0.f, 0.f, 0.f, 0.f};

  long arow0 = (long)mt * 128;
  long brow0 = (long)nt * 128;
  int srow = w * 8 + (l >> 3);
  int scol = (l & 7) * 8;
  const u16* ag = A + (arow0 + srow) * 1024 + scol;
  const u16* bg = BT + (brow0 + srow) * 1024 + scol;
  u16* asl = &As[srow][scol];
  u16* bsl = &Bs[srow][scol];

  for (int kt = 0; kt < 16; ++kt) {
    int ko = kt * 64;
    #pragma unroll
    for (int p = 0; p < 4; ++p)
      __builtin_amdgcn_global_load_lds(
          (const __attribute__((address_space(1))) void*)(ag + (long)p * 32 * 1024 + ko),
          (__attribute__((address_space(3))) void*)(asl + p * 32 * 64), 16, 0, 0);
    #pragma unroll
    for (int p = 0; p < 4; ++p)
      __builtin_amdgcn_global_load_lds(
          (const __attribute__((address_space(1))) void*)(bg + (long)p * 32 * 1024 + ko),
          (__attribute__((address_space(3))) void*)(bsl + p * 32 * 64), 16, 0, 0);
    __syncthreads();
    #pragma unroll
    for (int kk = 0; kk < 2; ++kk) {
      bf16x8 af[4], bfr[4];
      #pragma unroll
      for (int m = 0; m < 4; ++m)
        af[m] = *(const bf16x8*)&As[wr * 64 + m * 16 + lr][kk * 32 + lh * 8];
      #pragma unroll
      for (int n = 0; n < 4; ++n)
        bfr[n] = *(const bf16x8*)&Bs[wc * 64 + n * 16 + lr][kk * 32 + lh * 8];
      #pragma unroll
      for (int m = 0; m < 4; ++m)
        #pragma unroll
        for (int n = 0; n < 4; ++n)
          acc[m][n] = MFMA16(af[m], bfr[n], acc[m][n]);
    }
    __syncthreads();
  }

  #pragma unroll
  for (int m = 0; m < 4; ++m) {
    #pragma unroll
    for (int n = 0; n < 4; ++n) {
      #pragma unroll
      for (int r = 0; r < 4; ++r) {
        int row = (int)arow0 + wr * 64 + m * 16 + lh * 4 + r;
        int col = (int)brow0 + wc * 64 + n * 16 + lr;
        float v = acc[m][n][r];
        if constexpr (MODE == 2) {
          if (row < 784) {
            v += bias[col];
            int b = row / 49, qi = row - b * 49;
            long addr = ((long)(b * 16 + (col >> 6)) * 64 + qi) * 64 + (col & 63);
            ((u16*)outp)[addr] = f2bf(v);
          }
        } else {
          if (row < 784) {
            v += bias[col];
            ((float*)outp)[(long)row * 1024 + col] = v;
          }
        }
      }
    }
  }
}

// ---------------- fused attention partials: one wg per (b,h,s-chunk) ---------
__global__ __launch_bounds__(512, 2) void attn_part(
    const u16* __restrict__ Kt, const u16* __restrict__ Vt, const u16* __restrict__ Q,
    const float* __restrict__ mask,
    float* __restrict__ partA, float* __restrict__ prs)
{
  __shared__ u16 Plds[8192];
  __shared__ float red[4][4][4][64];
  __shared__ float redrs[4][4][64];

  int bh = blockIdx.x;
  int chunk = blockIdx.y;
  int tid = threadIdx.x;
  int l = tid & 63, w = tid >> 6;
  int qm = w & 3, sh = w >> 2;
  int lr = l & 15, lh = l >> 4;

  const u16* Kb = Kt + (long)bh * 262144;   // [s][d] rows of 64
  const u16* Vb = Vt + (long)bh * 262144;   // [d][s] rows of 4096
  const u16* Qb = Q  + (long)bh * 4096;     // [qi][d]

  bf16x8 qf[2];
  #pragma unroll
  for (int kf = 0; kf < 2; ++kf)
    qf[kf] = *(const bf16x8*)(Qb + (qm * 16 + lr) * 64 + kf * 32 + lh * 8);

  bf16x8 ones;
  #pragma unroll
  for (int j = 0; j < 8; ++j) ones[j] = (__bf16)1.0f;

  f32x4 acc_a[4];
  #pragma unroll
  for (int n = 0; n < 4; ++n) acc_a[n] = f32x4{0.f, 0.f, 0.f, 0.f};
  f32x4 acc_rs = f32x4{0.f, 0.f, 0.f, 0.f};

  char* Pw = (char*)Plds + w * 2048;

  for (int it = 0; it < 8; ++it) {
    int s0 = chunk * 1024 + (it * 2 + sh) * 64;
    f32x4 lg[4];
    #pragma unroll
    for (int sf = 0; sf < 4; ++sf) {
      const u16* kp = Kb + (long)(s0 + sf * 16 + lr) * 64 + lh * 8;
      bf16x8 k0 = *(const bf16x8*)(kp);
      bf16x8 k1 = *(const bf16x8*)(kp + 32);
      f32x4 t = f32x4{0.f, 0.f, 0.f, 0.f};
      t = MFMA16(qf[0], k0, t);
      t = MFMA16(qf[1], k1, t);
      lg[sf] = t;
    }
    #pragma unroll
    for (int sf = 0; sf < 4; ++sf) {
      #pragma unroll
      for (int r = 0; r < 4; ++r) {
        int qq = lh * 4 + r;
        int q = qm * 16 + qq;
        int s = s0 + sf * 16 + lr;
        float mv = (q < 49) ? mask[(long)q * 4096 + s] : 0.f;
        float e = __expf(lg[sf][r] * 0.125f) * mv;
        int byte = (qq * 128 + (sf * 16 + lr) * 2) ^ ((qq & 7) << 4);
        *(u16*)(Pw + byte) = f2bf(e);
      }
    }
    #pragma unroll
    for (int k2 = 0; k2 < 2; ++k2) {
      int byte = (lr * 128 + k2 * 64 + lh * 16) ^ ((lr & 7) << 4);
      bf16x8 pf;
      __builtin_memcpy(&pf, Pw + byte, 16);
      #pragma unroll
      for (int n = 0; n < 4; ++n) {
        bf16x8 vf = *(const bf16x8*)(Vb + (long)(n * 16 + lr) * 4096 + s0 + k2 * 32 + lh * 8);
        acc_a[n] = MFMA16(pf, vf, acc_a[n]);
      }
      acc_rs = MFMA16(pf, ones, acc_rs);
    }
  }

  if (sh == 1) {
    #pragma unroll
    for (int n = 0; n < 4; ++n)
      #pragma unroll
      for (int r = 0; r < 4; ++r)
        red[qm][n][r][l] = acc_a[n][r];
    #pragma unroll
    for (int r = 0; r < 4; ++r) redrs[qm][r][l] = acc_rs[r];
  }
  __syncthreads();
  if (sh == 0) {
    long base = ((long)bh * 4 + chunk) * 64;
    #pragma unroll
    for (int r = 0; r < 4; ++r) {
      int q = qm * 16 + lh * 4 + r;
      float rs = acc_rs[r] + redrs[qm][r][l];
      if (lr == 0) prs[base + q] = rs;
      #pragma unroll
      for (int n = 0; n < 4; ++n)
        partA[(base + q) * 64 + n * 16 + lr] = acc_a[n][r] + red[qm][n][r][l];
    }
  }
}

// ---------------- reduce 4 s-chunk partials, normalize, write a_bf -----------
__global__ __launch_bounds__(256) void attn_reduce(
    const float* __restrict__ partA, const float* __restrict__ prs,
    u16* __restrict__ Abf)
{
  int bh = blockIdx.x;
  int t = threadIdx.x;
  int q = t >> 2, d0 = (t & 3) * 16;
  if (q >= 49) return;
  int b = bh >> 4, h = bh & 15;

  float rs = 1e-6f;
  #pragma unroll
  for (int c = 0; c < 4; ++c) rs += prs[((long)bh * 4 + c) * 64 + q];

  #pragma unroll
  for (int j = 0; j < 4; ++j) {
    float4 s = float4{0.f, 0.f, 0.f, 0.f};
    #pragma unroll
    for (int c = 0; c < 4; ++c) {
      float4 v = *(const float4*)(partA + (((long)bh * 4 + c) * 64 + q) * 64 + d0 + j * 4);
      s.x += v.x; s.y += v.y; s.z += v.z; s.w += v.w;
    }
    ushort4 o;
    o.x = f2bf(s.x / rs); o.y = f2bf(s.y / rs);
    o.z = f2bf(s.z / rs); o.w = f2bf(s.w / rs);
    *(ushort4*)(Abf + ((long)(b * 49 + q) * 1024 + h * 64 + d0 + j * 4)) = o;
  }
}

// -----------------------------------------------------------------------------
extern "C" void kernel_launch(void* const* d_in, const int* in_sizes, int n_in,
                              void* d_out, int out_size, void* d_ws, size_t ws_size,
                              hipStream_t stream) {
  const float* x      = (const float*)d_in[0];
  const float* y      = (const float*)d_in[1];
  const float* mask   = (const float*)d_in[2];
  const float* W_attn = (const float*)d_in[3];
  const float* b_attn = (const float*)d_in[4];
  const float* W_mlp  = (const float*)d_in[5];
  const float* b_mlp  = (const float*)d_in[6];
  const float* W_proj = (const float*)d_in[7];
  const float* b_proj = (const float*)d_in[8];

  if (ws_size < 416808960ULL) return;

  char* ws = (char*)d_ws;
  u16* x_bf    = (u16*)(ws);                   // 128 MB  [65536][1024]
  u16* Kt      = (u16*)(ws + 134217728L);      // 128 MB  [b][h][s][d]
  u16* Vt      = (u16*)(ws + 268435456L);      // 128 MB  [b][h][d][s]
  u16* WT_attn = (u16*)(ws + 402653184L);      // 4 MB    [2048][1024]
  u16* WT_mlp  = (u16*)(ws + 406847488L);      // 2 MB
  u16* WT_proj = (u16*)(ws + 408944640L);      // 2 MB
  u16* y_bf    = (u16*)(ws + 411041792L);      // 1.75 MB [896][1024] zero-padded
  u16* q_ws    = (u16*)(ws + 412876800L);      // 2 MB    [b][h][64][64]
  u16* a_bf    = (u16*)(ws + 414973952L);      // 1.75 MB [896][1024]
  // attention partials REUSE the x_bf region (dead after gemm256<1>)
  float* partA = (float*)(ws);                 // 16 MB
  float* prs   = (float*)(ws + 16777216L);     // 256 KB

  cast_f32_bf16<<<2048, 256, 0, stream>>>(x, x_bf, 16777216, 16777216);
  cast_f32_bf16<<<896, 256, 0, stream>>>(y, y_bf, 200704, 229376);
  transpose_cast<<<dim3(32, 16), 256, 0, stream>>>(W_attn, WT_attn, 1024, 2048);
  transpose_cast<<<dim3(16, 16), 256, 0, stream>>>(W_mlp, WT_mlp, 1024, 1024);
  transpose_cast<<<dim3(16, 16), 256, 0, stream>>>(W_proj, WT_proj, 1024, 1024);

  gemm256<0><<<1024, 512, 0, stream>>>(x_bf, WT_attn, b_attn, Kt);
  gemm256<1><<<dim3(64, 16), 512, 0, stream>>>(WT_attn + 1048576, x_bf, b_attn, Vt);
  gemm_bt<2><<<56, 256, 0, stream>>>(y_bf, WT_mlp, b_mlp, q_ws);

  attn_part<<<dim3(256, 4), 512, 0, stream>>>(Kt, Vt, q_ws, mask, partA, prs);
  attn_reduce<<<256, 256, 0, stream>>>(partA, prs, a_bf);

  gemm_bt<3><<<56, 256, 0, stream>>>(a_bf, WT_proj, b_proj, d_out);
}